// Round 3
// baseline (121.834 us; speedup 1.0000x reference)
//
#include <hip/hip_runtime.h>
#include <cfloat>

// Chamfer L1, pred [B,N,3], gt [B,M,3] fp32, N==M==4096, B==4.
// R3: dispatch-count attack. Evidence R0-R2: inner loop is at the VALU floor
//     (~10-12us of 805M ops); total time tracks dispatch count + ws bytes.
//     -> 2 dispatches total:
//     (1) one 128KB+64B memset(0xFF): atomicMin array AND done-counter
//         (init -1; k-th arrival's fetch_add returns k-2, last sees nblocks-2).
//     (2) fused kernel: per (dir,b,query-chunk,target-chunk) block computes
//         per-query min over SoA-staged LDS targets (3x ds_read_b128 per 4
//         targets, v_min3-shaped min chain), atomicMin into the 128KB array,
//         then last-finisher block re-reads it with agent-scope atomic loads
//         (cross-XCD coherent) and writes the final scalar. No memset(out),
//         no second kernel.

constexpr int TPB = 256;
constexpr int PTS = 4;            // query points per thread
constexpr int NC  = TPB * PTS;    // 1024 queries per block
constexpr int MC  = 256;          // targets staged in LDS per block

__global__ __launch_bounds__(TPB) void chamfer_fused_kernel(
    const float* __restrict__ pred, const float* __restrict__ gt,
    unsigned* __restrict__ wsmin, unsigned* __restrict__ counter,
    float* __restrict__ out,
    int B, int N, int M, int nblocks, float inv) {
    const int dir = blockIdx.z;
    const int b   = blockIdx.y;
    const float* q = dir ? gt   : pred;
    const float* t = dir ? pred : gt;
    const int Nq   = dir ? M : N;
    const int Nt   = dir ? N : M;
    const int nchunks = Nq / NC;              // 4
    const int nc = blockIdx.x % nchunks;
    const int mc = blockIdx.x / nchunks;      // 0..Nt/MC-1 (15)

    __shared__ __align__(16) float lds[3 * MC];   // SoA: x[256] y[256] z[256]
    __shared__ float red[4];
    __shared__ int lastFlag;

    // Stage target chunk (256 pts x 12 B) into LDS, SoA transpose.
    const float* tbase = t + ((size_t)b * Nt + (size_t)mc * MC) * 3;
    for (int i = threadIdx.x; i < MC * 3; i += TPB) {
        lds[(i % 3) * MC + i / 3] = tbase[i];
    }
    __syncthreads();

    // 4 query points per thread, in registers.
    const float* qb = q + (size_t)b * Nq * 3;
    float px[PTS], py[PTS], pz[PTS], mn[PTS];
    int n[PTS];
#pragma unroll
    for (int i = 0; i < PTS; ++i) {
        n[i] = nc * NC + threadIdx.x + i * TPB;
        px[i] = qb[n[i] * 3 + 0];
        py[i] = qb[n[i] * 3 + 1];
        pz[i] = qb[n[i] * 3 + 2];
        mn[i] = FLT_MAX;
    }

    // 4 targets per iter: 3 broadcast ds_read_b128, min3-shaped chain.
#pragma unroll 2
    for (int j = 0; j < MC; j += 4) {
        float4 gx = *(const float4*)&lds[j];
        float4 gy = *(const float4*)&lds[MC + j];
        float4 gz = *(const float4*)&lds[2 * MC + j];
#pragma unroll
        for (int i = 0; i < PTS; ++i) {
            float d0 = fabsf(px[i] - gx.x) + fabsf(py[i] - gy.x) + fabsf(pz[i] - gz.x);
            float d1 = fabsf(px[i] - gx.y) + fabsf(py[i] - gy.y) + fabsf(pz[i] - gz.y);
            float d2 = fabsf(px[i] - gx.z) + fabsf(py[i] - gy.z) + fabsf(pz[i] - gz.z);
            float d3 = fabsf(px[i] - gx.w) + fabsf(py[i] - gy.w) + fabsf(pz[i] - gz.w);
            mn[i] = fminf(mn[i], fminf(d0, d1));   // v_min3_f32
            mn[i] = fminf(mn[i], fminf(d2, d3));   // v_min3_f32
        }
    }

    // One atomicMin per query per target-chunk (d >= 0 -> float bits monotone
    // as uint). Array is L2/coherent-point resident, 128KB.
    unsigned* outp = wsmin + ((size_t)dir * B + b) * N;
#pragma unroll
    for (int i = 0; i < PTS; ++i)
        atomicMin(&outp[n[i]], __float_as_uint(mn[i]));

    // Last-finisher block does the final sum. Counter was memset to
    // 0xFFFFFFFF: k-th arrival's fetch_add returns k-2 (mod 2^32), so the
    // nblocks-th (last) arrival sees nblocks-2.
    __threadfence();
    if (threadIdx.x == 0) {
        unsigned old = __hip_atomic_fetch_add(counter, 1u, __ATOMIC_ACQ_REL,
                                              __HIP_MEMORY_SCOPE_AGENT);
        lastFlag = (old == (unsigned)(nblocks - 2));
    }
    __syncthreads();
    if (!lastFlag) return;
    __threadfence();

    // Sum 2*B*N mins (as 16384 x 8B agent-scope loads: coherent vs the
    // device-scope atomicMins from other XCDs), scale, block-reduce, store.
    const unsigned long long* w2 = (const unsigned long long*)wsmin;
    const int total2 = B * N;   // 2*B*N/2
    float v = 0.0f;
    for (int i = threadIdx.x; i < total2; i += TPB) {
        unsigned long long u = __hip_atomic_load(&w2[i], __ATOMIC_RELAXED,
                                                 __HIP_MEMORY_SCOPE_AGENT);
        v += __uint_as_float((unsigned)u) + __uint_as_float((unsigned)(u >> 32));
    }
    v *= inv;

    for (int off = 32; off > 0; off >>= 1) v += __shfl_down(v, off, 64);
    const int lane = threadIdx.x & 63, w = threadIdx.x >> 6;
    if (lane == 0) red[w] = v;
    __syncthreads();
    if (threadIdx.x == 0)
        *out = red[0] + red[1] + red[2] + red[3];
}

extern "C" void kernel_launch(void* const* d_in, const int* in_sizes, int n_in,
                              void* d_out, int out_size, void* d_ws, size_t ws_size,
                              hipStream_t stream) {
    const float* pred = (const float*)d_in[0];
    const float* gt   = (const float*)d_in[1];
    float* out = (float*)d_out;

    const int B = 4;
    const int N = in_sizes[0] / (B * 3);   // 4096
    const int M = in_sizes[1] / (B * 3);   // 4096

    unsigned* wsmin   = (unsigned*)d_ws;            // [2][B][N] uints = 128 KB
    const int Q = 2 * B * N;                        // 32768
    unsigned* counter = wsmin + Q;                  // one uint after the array

    // Single memset: 0xFF = +inf-ish float bits for wsmin AND -1 counter init.
    hipMemsetAsync(d_ws, 0xFF, (size_t)(Q + 16) * sizeof(unsigned), stream);

    dim3 grid((N / NC) * (M / MC), B, 2);   // 64 x 4 x 2 = 512 blocks
    const int nblocks = grid.x * grid.y * grid.z;
    chamfer_fused_kernel<<<grid, TPB, 0, stream>>>(
        pred, gt, wsmin, counter, out, B, N, M, nblocks,
        1.0f / (float)(B * N));   // mean scale, equal for both dirs since N==M
}

// Round 4
// 80.639 us; speedup vs baseline: 1.5109x; 1.5109x over previous
//
#include <hip/hip_runtime.h>
#include <cfloat>

// Chamfer L1, pred [B,N,3], gt [B,M,3] fp32, N==M==4096, B==4.
// R4: revert to R0's 3-dispatch structure (77.7us measured; R3's fused
//     atomics/fence/last-block variant was 70us for the kernel alone).
//     R3's counters showed the partial kernel is latency-bound (~30us vs
//     9.4us VALU floor, VALUBusy 23%, 2 waves/SIMD). Two fixes:
//     (1) targets are wave-uniform -> stream them through the SCALAR pipe
//         (s_load into SGPRs): no LDS staging, no __syncthreads, no ds_read;
//         VALU is the sole vector-pipe consumer, SMEM prefetch overlaps free.
//     (2) PTS 4->2 (NC=512) -> 1024 blocks = 4 waves/SIMD at UNCHANGED 2MB
//         workspace (ws is keyed by mc-count only) — the occupancy bump
//         without R1's traffic confound.
// Kernel 2 (unchanged R0): min over 16 mc-chunks, scale, block-sum,
//     one atomicAdd per block into d_out (memset to 0 first).

constexpr int TPB = 256;
constexpr int PTS = 2;            // query points per thread
constexpr int NC  = TPB * PTS;    // 512 queries per block
constexpr int MC  = 256;          // targets per chunk (16 chunks -> 2MB ws)

__global__ __launch_bounds__(TPB) void chamfer_partial_kernel(
    const float* __restrict__ pred, const float* __restrict__ gt,
    float* __restrict__ partial, int B, int N, int M) {
    const int dir = blockIdx.z;
    const int b   = blockIdx.y;
    const float* __restrict__ q = dir ? gt   : pred;
    const float* __restrict__ t = dir ? pred : gt;
    const int Nq   = dir ? M : N;
    const int Nt   = dir ? N : M;
    const int nchunks = Nq / NC;              // 8
    const int nc = blockIdx.x % nchunks;
    const int mc = blockIdx.x / nchunks;      // 0..Nt/MC-1 (15)

    // Wave-uniform target base: loads below should scalarize (s_load).
    const float* __restrict__ tb = t + ((size_t)b * Nt + (size_t)mc * MC) * 3;
    const float* __restrict__ qb = q + (size_t)b * Nq * 3;

    // 2 query points per thread, in registers.
    float px[PTS], py[PTS], pz[PTS], mn[PTS];
    int n[PTS];
#pragma unroll
    for (int i = 0; i < PTS; ++i) {
        n[i] = nc * NC + threadIdx.x + i * TPB;
        px[i] = qb[n[i] * 3 + 0];
        py[i] = qb[n[i] * 3 + 1];
        pz[i] = qb[n[i] * 3 + 2];
        mn[i] = FLT_MAX;
    }

    // 2 targets per iter from the scalar pipe; min3-shaped chain.
#pragma unroll 8
    for (int j = 0; j < MC; j += 2) {
        const float gx0 = tb[j * 3 + 0], gy0 = tb[j * 3 + 1], gz0 = tb[j * 3 + 2];
        const float gx1 = tb[j * 3 + 3], gy1 = tb[j * 3 + 4], gz1 = tb[j * 3 + 5];
#pragma unroll
        for (int i = 0; i < PTS; ++i) {
            float d0 = fabsf(px[i] - gx0) + fabsf(py[i] - gy0) + fabsf(pz[i] - gz0);
            float d1 = fabsf(px[i] - gx1) + fabsf(py[i] - gy1) + fabsf(pz[i] - gz1);
            mn[i] = fminf(mn[i], fminf(d0, d1));   // v_min3_f32 candidate
        }
    }

    // partial[mc][dir][b][n] — coalesced stores.
    float* outp = partial + (((size_t)mc * 2 + dir) * B + b) * N;
#pragma unroll
    for (int i = 0; i < PTS; ++i) outp[n[i]] = mn[i];
}

__global__ __launch_bounds__(256) void chamfer_reduce_kernel(
    const float* __restrict__ partial, float* __restrict__ out,
    int Q, float inv) {
    const int qidx = blockIdx.x * 256 + threadIdx.x;
    float mn = FLT_MAX;
#pragma unroll
    for (int mc = 0; mc < 16; ++mc)   // nmc == 16 for N==M==4096, MC==256
        mn = fminf(mn, partial[(size_t)mc * Q + qidx]);
    float v = mn * inv;

    // wave-64 shuffle reduce, then cross-wave via LDS
    for (int off = 32; off > 0; off >>= 1) v += __shfl_down(v, off, 64);
    __shared__ float red[4];
    const int lane = threadIdx.x & 63, w = threadIdx.x >> 6;
    if (lane == 0) red[w] = v;
    __syncthreads();
    if (threadIdx.x == 0)
        atomicAdd(out, red[0] + red[1] + red[2] + red[3]);
}

extern "C" void kernel_launch(void* const* d_in, const int* in_sizes, int n_in,
                              void* d_out, int out_size, void* d_ws, size_t ws_size,
                              hipStream_t stream) {
    const float* pred = (const float*)d_in[0];
    const float* gt   = (const float*)d_in[1];
    float* out = (float*)d_out;

    const int B = 4;
    const int N = in_sizes[0] / (B * 3);   // 4096
    const int M = in_sizes[1] / (B * 3);   // 4096

    float* partial = (float*)d_ws;          // [16][2][B][N] floats = 2 MB
    const int Q = 2 * B * N;                // 32768

    hipMemsetAsync(out, 0, sizeof(float), stream);

    dim3 grid((N / NC) * (M / MC), B, 2);   // 128 x 4 x 2 = 1024 blocks
    chamfer_partial_kernel<<<grid, TPB, 0, stream>>>(pred, gt, partial, B, N, M);

    // mean scale: 1/(B*N) for dir0, 1/(B*M) for dir1 — equal since N==M.
    chamfer_reduce_kernel<<<Q / 256, 256, 0, stream>>>(
        partial, out, Q, 1.0f / (float)(B * N));
}

// Round 5
// 75.101 us; speedup vs baseline: 1.6223x; 1.0737x over previous
//
#include <hip/hip_runtime.h>
#include <cfloat>

// Chamfer L1, pred [B,N,3], gt [B,M,3] fp32, N==M==4096, B==4.
// R5: R0 structure EXACTLY (512 blocks, PTS=4, MC=256, LDS float4 broadcast,
//     3 dispatches, 2MB partial ws) — proven best at 77.7us. Single change:
//     the inner per-pair arithmetic is pinned with inline asm so the emitted
//     mix is exactly 5.5 VALU/pair:
//       3x v_sub_f32 (C)  — sign irrelevant under abs
//       2x v_add_f32_e64 with |.| input modifiers (abs folded, free)
//       0.5x v_min3_f32 (one min per two targets)
//     Evidence: R1 (2x waves), R4 (2x blocks, scalar feed), R2 (min3 shaping)
//     were ALL null -> kernel is VALU-issue-throughput bound, yet sits at
//     2.4x the 6-op/pair floor -> codegen must be fat (~14 ops/pair). This
//     forces ~5.5/pair (9.4us floor; predict partial ~12-14us).

constexpr int TPB = 256;
constexpr int PTS = 4;            // query points per thread
constexpr int NC  = TPB * PTS;    // 1024 queries per block
constexpr int MC  = 256;          // targets staged in LDS per block

__global__ __launch_bounds__(TPB) void chamfer_partial_kernel(
    const float* __restrict__ pred, const float* __restrict__ gt,
    float* __restrict__ partial, int B, int N, int M) {
    const int dir = blockIdx.z;
    const int b   = blockIdx.y;
    const float* q = dir ? gt   : pred;
    const float* t = dir ? pred : gt;
    const int Nq   = dir ? M : N;
    const int Nt   = dir ? N : M;
    const int nchunks = Nq / NC;              // 4
    const int nc = blockIdx.x % nchunks;
    const int mc = blockIdx.x / nchunks;      // 0..Nt/MC-1 (15)

    __shared__ float4 lds4[MC];               // w unused; 4 KB

    // Stage target chunk (256 pts x 12 B) into LDS as padded float4.
    const float* tbase = t + ((size_t)b * Nt + (size_t)mc * MC) * 3;
    for (int i = threadIdx.x; i < MC * 3; i += TPB) {
        ((float*)&lds4[i / 3])[i % 3] = tbase[i];
    }
    __syncthreads();

    // 4 query points per thread, in registers.
    const float* qb = q + (size_t)b * Nq * 3;
    float px[PTS], py[PTS], pz[PTS], mn[PTS];
    int n[PTS];
#pragma unroll
    for (int i = 0; i < PTS; ++i) {
        n[i] = nc * NC + threadIdx.x + i * TPB;
        px[i] = qb[n[i] * 3 + 0];
        py[i] = qb[n[i] * 3 + 1];
        pz[i] = qb[n[i] * 3 + 2];
        mn[i] = FLT_MAX;
    }

    // Two targets per iter (2 broadcast ds_read_b128), asm-pinned arithmetic:
    // per (query, target-pair): 6 sub + 4 add(|.|) + 1 min3 = 11 VALU.
#pragma unroll 4
    for (int j = 0; j < MC; j += 2) {
        float4 g0 = lds4[j];      // broadcast — all lanes same addr
        float4 g1 = lds4[j + 1];
#pragma unroll
        for (int i = 0; i < PTS; ++i) {
            float dx0 = px[i] - g0.x, dy0 = py[i] - g0.y, dz0 = pz[i] - g0.z;
            float dx1 = px[i] - g1.x, dy1 = py[i] - g1.y, dz1 = pz[i] - g1.z;
            float s0, s1, d0, d1;
            asm("v_add_f32_e64 %0, |%1|, |%2|" : "=v"(s0) : "v"(dx0), "v"(dy0));
            asm("v_add_f32_e64 %0, %1, |%2|"   : "=v"(d0) : "v"(s0),  "v"(dz0));
            asm("v_add_f32_e64 %0, |%1|, |%2|" : "=v"(s1) : "v"(dx1), "v"(dy1));
            asm("v_add_f32_e64 %0, %1, |%2|"   : "=v"(d1) : "v"(s1),  "v"(dz1));
            asm("v_min3_f32 %0, %0, %1, %2"    : "+v"(mn[i]) : "v"(d0), "v"(d1));
        }
    }

    // partial[mc][dir][b][n] — coalesced stores (N==M assumed for stride).
    float* outp = partial + (((size_t)mc * 2 + dir) * B + b) * N;
#pragma unroll
    for (int i = 0; i < PTS; ++i) outp[n[i]] = mn[i];
}

__global__ __launch_bounds__(256) void chamfer_reduce_kernel(
    const float* __restrict__ partial, float* __restrict__ out,
    int Q, float inv) {
    const int qidx = blockIdx.x * 256 + threadIdx.x;
    float mn = FLT_MAX;
#pragma unroll
    for (int mc = 0; mc < 16; ++mc)   // nmc == 16 for N==M==4096, MC==256
        mn = fminf(mn, partial[(size_t)mc * Q + qidx]);
    float v = mn * inv;

    // wave-64 shuffle reduce, then cross-wave via LDS
    for (int off = 32; off > 0; off >>= 1) v += __shfl_down(v, off, 64);
    __shared__ float red[4];
    const int lane = threadIdx.x & 63, w = threadIdx.x >> 6;
    if (lane == 0) red[w] = v;
    __syncthreads();
    if (threadIdx.x == 0)
        atomicAdd(out, red[0] + red[1] + red[2] + red[3]);
}

extern "C" void kernel_launch(void* const* d_in, const int* in_sizes, int n_in,
                              void* d_out, int out_size, void* d_ws, size_t ws_size,
                              hipStream_t stream) {
    const float* pred = (const float*)d_in[0];
    const float* gt   = (const float*)d_in[1];
    float* out = (float*)d_out;

    const int B = 4;
    const int N = in_sizes[0] / (B * 3);   // 4096
    const int M = in_sizes[1] / (B * 3);   // 4096

    float* partial = (float*)d_ws;          // [16][2][B][N] floats = 2 MB
    const int Q = 2 * B * N;                // 32768

    hipMemsetAsync(out, 0, sizeof(float), stream);

    dim3 grid((N / NC) * (M / MC), B, 2);   // 64 x 4 x 2 = 512 blocks
    chamfer_partial_kernel<<<grid, TPB, 0, stream>>>(pred, gt, partial, B, N, M);

    // mean scale: 1/(B*N) for dir0, 1/(B*M) for dir1 — equal since N==M.
    chamfer_reduce_kernel<<<Q / 256, 256, 0, stream>>>(
        partial, out, Q, 1.0f / (float)(B * N));
}